// Round 9
// baseline (305.212 us; speedup 1.0000x reference)
//
#include <hip/hip_runtime.h>
#include <stdint.h>

// Problem constants (fixed by the reference file)
#define N_POS (16 * 65536)   // B * L = 1,048,576 positions
#define NBINS 256
#define HDIM  64

// RESOLVED DTYPE MAP (rounds 0-8 forensic summary):
//   - r8's on-device detector proved all three inputs are FULL-PRECISION FP32
//     (bf16-plausibility scans failed on x/emb low-mantissa halves; bins
//     bf16-read unsorted) -> flags=(0,0,0), r8 degenerated to r3 bit-exactly.
//   - r5's raw-chunk copy of that fp32 emb produced absmax 7.16, not ~1e38
//     -> output CANNOT be read back as uint16<<16 -> the harness's executed
//     readback branch is float32. Stub docs agree: reference output dtype is
//     fp32 -> d_out is float*. The "(bf16, ...)" label is only the tolerance.
//   - Every prior round wrote 128 MB of packed bf16 into the 256 MB f32
//     buffer: first half = (bf16,bf16) pairs read as f32 (bounded garbage),
//     second half = memset 0 -> explains every bounded absmax and the
//     bit-identical repeats (saturated max). The ONLY bug since round 0 was
//     the output dtype/size.

typedef float vfloat4 __attribute__((ext_vector_type(4)));  // OK for nontemporal builtin

// One thread = one 16B float4 chunk (4 f32) of one output row.
// 16 lanes cooperate on one position (redundant token compute, coalesced stores).
__global__ __launch_bounds__(256) void BinEmbedding_49520972923592_kernel(
    const float* __restrict__ x,        // (B*L) fp32
    const float* __restrict__ bins,     // (256) fp32, sorted
    const vfloat4* __restrict__ embv,   // (257,64) fp32 = 16 x float4 chunks per row
    vfloat4* __restrict__ out)          // (B*L,64) fp32 = 16 x float4 chunks per row
{
    __shared__ float s_bins[NBINS];
    s_bins[threadIdx.x] = bins[threadIdx.x];   // blockDim == NBINS == 256
    __syncthreads();

    const int t   = blockIdx.x * 256 + threadIdx.x; // global float4-chunk index
    const int pos = t >> 4;                         // position in [0, N_POS)
    const int sub = t & 15;                         // which float4 of the 64-f32 row

    const float xv = x[pos];

    // count = #bins <= xv (branchless upper-bound binary search; steps sum to
    // 255 -> min(count,255); top-edge test lifts count==256, fires only when
    // x >= bins[255]). NaN x: all compares false -> cnt = 0.
    int cnt = 0;
#pragma unroll
    for (int step = 128; step >= 1; step >>= 1) {
        const int cand = cnt + step;
        cnt = (s_bins[cand - 1] <= xv) ? cand : cnt;
    }
    cnt += (s_bins[NBINS - 1] <= xv) ? 1 : 0;

    // tok = NaN ? 0 : max(count, 1)  (== clamp(searchsorted_right - 1, 0) + 1)
    const int tok = (xv != xv) ? 0 : (cnt > 0 ? cnt : 1);

    // Verbatim f32 gather of the row chunk — bit-exact vs the np reference.
    // Max index: 256*16+15 = 4111 chunks = 65,792 B = exactly the table size.
    const vfloat4 v = embv[tok * 16 + sub];
    __builtin_nontemporal_store(v, out + t);
}

extern "C" void kernel_launch(void* const* d_in, const int* in_sizes, int n_in,
                              void* d_out, int out_size, void* d_ws, size_t ws_size,
                              hipStream_t stream) {
    const float*   x    = (const float*)d_in[0];    // (16,65536) fp32
    const float*   bins = (const float*)d_in[1];    // (256,) fp32
    const vfloat4* emb  = (const vfloat4*)d_in[2];  // (257,64) fp32 chunks
    vfloat4* out = (vfloat4*)d_out;                 // (16,65536,64) fp32 chunks

    // N_POS positions x 16 chunk-lanes / 256 threads = 65536 blocks
    // (exact cover: 16.78M threads x 4 f32 = 67,108,864 f32 = out_size)
    const int total_threads = N_POS * 16;
    const dim3 grid(total_threads / 256), block(256);
    hipLaunchKernelGGL(BinEmbedding_49520972923592_kernel, grid, block, 0, stream,
                       x, bins, emb, out);
}

// Round 10
// 267.300 us; speedup vs baseline: 1.1418x; 1.1418x over previous
//
#include <hip/hip_runtime.h>
#include <stdint.h>

// Problem constants (fixed by the reference file)
#define N_POS (16 * 65536)   // B * L = 1,048,576 positions
#define NBINS 256
#define HDIM  64

// DTYPES (settled in rounds 0-9): x,bins,emb fp32 in; out fp32 (256 MB).
//
// ROUND 10 PERF THEORY:
//  - r9 = 305 us = 0.88 TB/s effective vs poison-fills' 6.2 TB/s on the SAME
//    buffer size class => the `nt` store flag is prime suspect (defeats L2
//    write combining). Plain stores here.
//  - r9 redundantly ran the binary search 16x per position (once per output
//    chunk). Split phases: tokens once per position (LDS), then 16 coalesced
//    float4 writes per thread with 16 independent gather loads in flight.

typedef float vfloat4 __attribute__((ext_vector_type(4)));

#define POS_PER_BLOCK 256
#define CHUNKS_PER_BLOCK (POS_PER_BLOCK * 16)   // 4096 float4 chunks = 64 KB out/block

__global__ __launch_bounds__(256) void BinEmbedding_49520972923592_kernel(
    const float* __restrict__ x,        // (B*L) fp32
    const float* __restrict__ bins,     // (256) fp32, sorted
    const vfloat4* __restrict__ embv,   // (257,64) fp32 = 16 float4 chunks per row
    vfloat4* __restrict__ out)          // (B*L,64) fp32 = 16 float4 chunks per row
{
    __shared__ float s_bins[NBINS];
    __shared__ int   s_tok[POS_PER_BLOCK];

    const int tid = threadIdx.x;
    s_bins[tid] = bins[tid];            // blockDim == NBINS == 256
    __syncthreads();

    // ---- Phase 1: one token per thread (1 search per position, was 16x) ----
    const int pos = blockIdx.x * POS_PER_BLOCK + tid;   // exact cover, no bounds
    const float xv = x[pos];

    // count = #bins <= xv (branchless upper-bound binary search; steps sum to
    // 255 -> min(count,255); top-edge test lifts count==256). NaN: cnt = 0.
    int cnt = 0;
#pragma unroll
    for (int step = 128; step >= 1; step >>= 1) {
        const int cand = cnt + step;
        cnt = (s_bins[cand - 1] <= xv) ? cand : cnt;
    }
    cnt += (s_bins[NBINS - 1] <= xv) ? 1 : 0;

    // tok = NaN ? 0 : max(count, 1)  (== clamp(searchsorted_right - 1, 0) + 1)
    s_tok[tid] = (xv != xv) ? 0 : (cnt > 0 ? cnt : 1);
    __syncthreads();

    // ---- Phase 2: 16 coalesced float4 chunk writes per thread -------------
    // Block covers chunks [b*4096, (b+1)*4096). Iteration i: consecutive
    // threads -> consecutive chunks (wave writes 1 KB contiguous, plain
    // stores -> L2 write combining). s_tok read: 16 consecutive tids share an
    // address (broadcast), 16 distinct banks -> conflict-free. 16 independent
    // gather loads in flight after unroll.
    const long base = (long)blockIdx.x * CHUNKS_PER_BLOCK;
#pragma unroll
    for (int i = 0; i < 16; ++i) {
        const int l   = i * 256 + tid;       // local chunk in [0,4096)
        const int tok = s_tok[l >> 4];       // position's token
        const vfloat4 v = embv[tok * 16 + (l & 15)];   // max 4111 < 4112 chunks
        out[base + l] = v;                   // plain store (no nt)
    }
}

extern "C" void kernel_launch(void* const* d_in, const int* in_sizes, int n_in,
                              void* d_out, int out_size, void* d_ws, size_t ws_size,
                              hipStream_t stream) {
    const float*   x    = (const float*)d_in[0];    // (16,65536) fp32
    const float*   bins = (const float*)d_in[1];    // (256,) fp32
    const vfloat4* emb  = (const vfloat4*)d_in[2];  // (257,64) fp32 chunks
    vfloat4* out = (vfloat4*)d_out;                 // (16,65536,64) fp32 chunks

    // 1,048,576 positions / 256 per block = 4096 blocks (16/CU), exact cover:
    // 4096 blocks x 64 KB = 268,435,456 B = out_size * 4.
    const dim3 grid(N_POS / POS_PER_BLOCK), block(256);
    hipLaunchKernelGGL(BinEmbedding_49520972923592_kernel, grid, block, 0, stream,
                       x, bins, emb, out);
}